// Round 1
// baseline (123.400 us; speedup 1.0000x reference)
//
#include <hip/hip_runtime.h>
#include <stdint.h>

#define BN_TOTAL 25600   // B*N = 256*100
#define DDIM 128
#define KN 16

typedef __bf16 bf16x8 __attribute__((ext_vector_type(8)));
typedef float f32x4 __attribute__((ext_vector_type(4)));
typedef unsigned short u16x8 __attribute__((ext_vector_type(8)));

__device__ __forceinline__ unsigned short f2bf(float x) {
    unsigned int u = __builtin_bit_cast(unsigned int, x);
    u = (u + 0x7fffu + ((u >> 16) & 1u)) >> 16;   // RNE
    return (unsigned short)u;
}

// ---------------- Kernel 1: attention + aggregation -> agg[BN][128] ----------
// One wave per (b,n). MFMA 16x16x32_bf16: M=16 neighbors, N=128 (8 tiles), K=128 (4 steps).
// Weight column (f=128) folded into accumulator init: acc = weight[r] * w1[128][d].
__global__ __launch_bounds__(256) void k1_attn_agg(
    const float* __restrict__ nbr,    // [BN,16,128]
    const float* __restrict__ wgt,    // [BN,16]
    const float* __restrict__ extra,  // [BN,128]
    const float* __restrict__ w1,     // [129,128]
    const float* __restrict__ w2,     // [128]
    float* __restrict__ agg)          // [BN,128]
{
    __shared__ uint4 b1frag[32][64];   // [t*4+s][lane] : w1 B-fragments, bf16x8, 32 KB
    __shared__ float w1last[DDIM];
    __shared__ float w2s[DDIM];
    __shared__ float aggbuf[4][DDIM];

    const int tid  = threadIdx.x;
    const int lane = tid & 63;
    const int wave = tid >> 6;
    const int grp  = lane >> 4;   // 0..3
    const int lr   = lane & 15;   // 0..15

    // ---- one-time per block: build w1 fragments (wave w fills k-step s=w)
    {
        const int s = wave;
        const int fbase = grp * 8 + 32 * s;
        for (int t = 0; t < 8; ++t) {
            const int d = t * 16 + lr;
            u16x8 tmp;
            #pragma unroll
            for (int j = 0; j < 8; ++j)
                tmp[j] = f2bf(w1[(fbase + j) * DDIM + d]);
            b1frag[t * 4 + s][lane] = __builtin_bit_cast(uint4, tmp);
        }
        if (tid < DDIM) {
            w1last[tid] = w1[DDIM * DDIM + tid];  // row 128 of w1
            w2s[tid]    = w2[tid];
        }
    }
    __syncthreads();

    const int stride = gridDim.x * 4;
    for (int bn = blockIdx.x * 4 + wave; bn < BN_TOTAL; bn += stride) {
        const float* nb = nbr   + (size_t)bn * (KN * DDIM);
        const float* ex = extra + (size_t)bn * DDIM;

        // acc init = weight[r] * w1[128][d]   (rows r = grp*4+j, col d = t*16+lr)
        const float4 wv = *(const float4*)(wgt + (size_t)bn * KN + grp * 4);
        f32x4 acc[8];
        #pragma unroll
        for (int t = 0; t < 8; ++t) {
            const float wl = w1last[t * 16 + lr];
            acc[t][0] = wv.x * wl;
            acc[t][1] = wv.y * wl;
            acc[t][2] = wv.z * wl;
            acc[t][3] = wv.w * wl;
        }

        float nreg[4][8];   // raw neighbor values, A-fragment layout (kept for agg)
        #pragma unroll
        for (int s = 0; s < 4; ++s) {
            const int f0 = grp * 8 + 32 * s;
            const float4 n0 = *(const float4*)(nb + lr * DDIM + f0);
            const float4 n1 = *(const float4*)(nb + lr * DDIM + f0 + 4);
            const float4 e0 = *(const float4*)(ex + f0);
            const float4 e1 = *(const float4*)(ex + f0 + 4);
            nreg[s][0] = n0.x; nreg[s][1] = n0.y; nreg[s][2] = n0.z; nreg[s][3] = n0.w;
            nreg[s][4] = n1.x; nreg[s][5] = n1.y; nreg[s][6] = n1.z; nreg[s][7] = n1.w;
            u16x8 au;
            au[0] = f2bf(n0.x * e0.x); au[1] = f2bf(n0.y * e0.y);
            au[2] = f2bf(n0.z * e0.z); au[3] = f2bf(n0.w * e0.w);
            au[4] = f2bf(n1.x * e1.x); au[5] = f2bf(n1.y * e1.y);
            au[6] = f2bf(n1.z * e1.z); au[7] = f2bf(n1.w * e1.w);
            const bf16x8 af = __builtin_bit_cast(bf16x8, au);
            #pragma unroll
            for (int t = 0; t < 8; ++t) {
                const bf16x8 bf = __builtin_bit_cast(bf16x8, b1frag[t * 4 + s][lane]);
                acc[t] = __builtin_amdgcn_mfma_f32_16x16x32_bf16(af, bf, acc[t], 0, 0, 0);
            }
        }

        // leaky_relu(0.2) + dot with w2 -> per-row partial sums (rows grp*4+j)
        float sum0 = 0.f, sum1 = 0.f, sum2 = 0.f, sum3 = 0.f;
        #pragma unroll
        for (int t = 0; t < 8; ++t) {
            const float w2v = w2s[t * 16 + lr];
            float h;
            h = acc[t][0]; h = fmaxf(h, 0.2f * h); sum0 = fmaf(h, w2v, sum0);
            h = acc[t][1]; h = fmaxf(h, 0.2f * h); sum1 = fmaf(h, w2v, sum1);
            h = acc[t][2]; h = fmaxf(h, 0.2f * h); sum2 = fmaf(h, w2v, sum2);
            h = acc[t][3]; h = fmaxf(h, 0.2f * h); sum3 = fmaf(h, w2v, sum3);
        }
        // reduce over the 16 lanes of the group (different d mod 16)
        #pragma unroll
        for (int m = 1; m <= 8; m <<= 1) {
            sum0 += __shfl_xor(sum0, m, 64);
            sum1 += __shfl_xor(sum1, m, 64);
            sum2 += __shfl_xor(sum2, m, 64);
            sum3 += __shfl_xor(sum3, m, 64);
        }
        // softmax over the 16 rows (groups hold rows 4g..4g+3)
        float mx = fmaxf(fmaxf(sum0, sum1), fmaxf(sum2, sum3));
        mx = fmaxf(mx, __shfl_xor(mx, 16, 64));
        mx = fmaxf(mx, __shfl_xor(mx, 32, 64));
        const float ev0 = __expf(sum0 - mx);
        const float ev1 = __expf(sum1 - mx);
        const float ev2 = __expf(sum2 - mx);
        const float ev3 = __expf(sum3 - mx);
        float es = ev0 + ev1 + ev2 + ev3;
        es += __shfl_xor(es, 16, 64);
        es += __shfl_xor(es, 32, 64);
        const float inv = 1.0f / es;

        // fetch alpha for this lane's row (= lr): lives on group lr>>2, slot lr&3
        const int src = ((lr >> 2) << 4) | lr;
        const float a0 = __shfl(ev0, src, 64);
        const float a1 = __shfl(ev1, src, 64);
        const float a2 = __shfl(ev2, src, 64);
        const float a3 = __shfl(ev3, src, 64);
        const int j0 = lr & 3;
        float myA = (j0 == 0) ? a0 : (j0 == 1) ? a1 : (j0 == 2) ? a2 : a3;
        myA *= inv;

        // agg[f] = sum_k alpha_k * nbr[k][f] : butterfly over the 16-lane group
        #pragma unroll
        for (int s = 0; s < 4; ++s) {
            #pragma unroll
            for (int j = 0; j < 8; ++j) {
                float v = myA * nreg[s][j];
                v += __shfl_xor(v, 1, 64);
                v += __shfl_xor(v, 2, 64);
                v += __shfl_xor(v, 4, 64);
                v += __shfl_xor(v, 8, 64);
                nreg[s][j] = v;
            }
        }
        // one writer per group pushes its 32 f-values to LDS, then coalesced store
        if (lr == 0) {
            #pragma unroll
            for (int s = 0; s < 4; ++s) {
                float4 lo, hi;
                lo.x = nreg[s][0]; lo.y = nreg[s][1]; lo.z = nreg[s][2]; lo.w = nreg[s][3];
                hi.x = nreg[s][4]; hi.y = nreg[s][5]; hi.z = nreg[s][6]; hi.w = nreg[s][7];
                *(float4*)&aggbuf[wave][grp * 8 + 32 * s]     = lo;
                *(float4*)&aggbuf[wave][grp * 8 + 32 * s + 4] = hi;
            }
        }
        __syncthreads();
        float* ao = agg + (size_t)bn * DDIM;
        ao[lane]      = aggbuf[wave][lane];
        ao[lane + 64] = aggbuf[wave][lane + 64];
    }
}

// ---------------- Kernel 2: out = relu([self | agg] @ w3) -------------------
// MFMA GEMM: M=25600 (16 rows/wave), K=256 (8 steps), N=128 (8 tiles).
__global__ __launch_bounds__(256) void k2_out_gemm(
    const float* __restrict__ selfv,  // [BN,128]
    const float* __restrict__ agg,    // [BN,128]
    const float* __restrict__ w3,     // [256,128]
    float* __restrict__ out)          // [BN,128]
{
    __shared__ uint4 w3frag[64][64];  // [t*8+s][lane], 64 KB

    const int tid  = threadIdx.x;
    const int lane = tid & 63;
    const int wave = tid >> 6;
    const int grp  = lane >> 4;
    const int lr   = lane & 15;

    #pragma unroll
    for (int si = 0; si < 2; ++si) {
        const int s = wave + si * 4;
        const int fbase = grp * 8 + 32 * s;
        for (int t = 0; t < 8; ++t) {
            const int d = t * 16 + lr;
            u16x8 tmp;
            #pragma unroll
            for (int j = 0; j < 8; ++j)
                tmp[j] = f2bf(w3[(fbase + j) * DDIM + d]);
            w3frag[t * 8 + s][lane] = __builtin_bit_cast(uint4, tmp);
        }
    }
    __syncthreads();

    const int rowbase = blockIdx.x * 64 + wave * 16;
    const int row = rowbase + lr;

    f32x4 acc[8];
    #pragma unroll
    for (int t = 0; t < 8; ++t) {
        acc[t][0] = 0.f; acc[t][1] = 0.f; acc[t][2] = 0.f; acc[t][3] = 0.f;
    }

    #pragma unroll
    for (int s = 0; s < 8; ++s) {
        const int f0 = grp * 8 + 32 * s;
        const float* srcp = (s < 4) ? (selfv + (size_t)row * DDIM + f0)
                                    : (agg   + (size_t)row * DDIM + (f0 - DDIM));
        const float4 x0 = *(const float4*)srcp;
        const float4 x1 = *(const float4*)(srcp + 4);
        u16x8 au;
        au[0] = f2bf(x0.x); au[1] = f2bf(x0.y); au[2] = f2bf(x0.z); au[3] = f2bf(x0.w);
        au[4] = f2bf(x1.x); au[5] = f2bf(x1.y); au[6] = f2bf(x1.z); au[7] = f2bf(x1.w);
        const bf16x8 af = __builtin_bit_cast(bf16x8, au);
        #pragma unroll
        for (int t = 0; t < 8; ++t) {
            const bf16x8 bf = __builtin_bit_cast(bf16x8, w3frag[t * 8 + s][lane]);
            acc[t] = __builtin_amdgcn_mfma_f32_16x16x32_bf16(af, bf, acc[t], 0, 0, 0);
        }
    }

    #pragma unroll
    for (int t = 0; t < 8; ++t) {
        #pragma unroll
        for (int j = 0; j < 4; ++j) {
            const int r = rowbase + grp * 4 + j;
            out[(size_t)r * DDIM + t * 16 + lr] = fmaxf(acc[t][j], 0.0f);
        }
    }
}

extern "C" void kernel_launch(void* const* d_in, const int* in_sizes, int n_in,
                              void* d_out, int out_size, void* d_ws, size_t ws_size,
                              hipStream_t stream)
{
    const float* selfv = (const float*)d_in[0];
    const float* nbr   = (const float*)d_in[1];
    const float* wgt   = (const float*)d_in[2];
    const float* extra = (const float*)d_in[3];
    const float* w1    = (const float*)d_in[4];
    const float* w2    = (const float*)d_in[5];
    const float* w3    = (const float*)d_in[6];
    float* out = (float*)d_out;
    float* agg = (float*)d_ws;   // BN*128 f32 = 13.1 MB scratch

    // 800 blocks * 4 waves = 3200 wave-slots; 25600/3200 = 8 uniform iterations
    hipLaunchKernelGGL(k1_attn_agg, dim3(800), dim3(256), 0, stream,
                       nbr, wgt, extra, w1, w2, agg);
    // 25600 rows / 64 rows-per-block = 400 blocks
    hipLaunchKernelGGL(k2_out_gemm, dim3(400), dim3(256), 0, stream,
                       selfv, agg, w3, out);
}